// Round 1
// baseline (3188.014 us; speedup 1.0000x reference)
//
#include <hip/hip_runtime.h>

#define NHEADS 4

// ---- monotonic float <-> unsigned encoding for atomicMax on floats ----
__device__ __forceinline__ unsigned enc_f(float f) {
  int i = __float_as_int(f);
  return (i >= 0) ? ((unsigned)i | 0x80000000u) : ~((unsigned)i);
}
__device__ __forceinline__ float dec_f(unsigned u) {
  int i = (u & 0x80000000u) ? (int)(u & 0x7fffffffu) : ~((int)u);
  return __int_as_float(i);
}

// ---- h = X[n,128] @ W[128,128], fp32 ----
__global__ __launch_bounds__(256) void k_gemm(const float* __restrict__ X,
                                              const float* __restrict__ W,
                                              float* __restrict__ H, int n) {
  __shared__ float Ws[128 * 128];  // 64 KB
  __shared__ float Xs[32 * 128];   // 16 KB
  const int tid = threadIdx.x;
  for (int i = tid; i < 4096; i += 256)
    ((float4*)Ws)[i] = ((const float4*)W)[i];
  const long row0 = (long)blockIdx.x * 32;
  for (int i = tid; i < 1024; i += 256) {
    long r = row0 + (i >> 5);
    if (r >= n) r = n - 1;
    ((float4*)Xs)[i] = ((const float4*)X)[r * 32 + (i & 31)];
  }
  __syncthreads();
  const int col = tid & 127, rg = tid >> 7;
  float acc[16];
#pragma unroll
  for (int r = 0; r < 16; ++r) acc[r] = 0.f;
  for (int k = 0; k < 128; ++k) {
    float w = Ws[k * 128 + col];
#pragma unroll
    for (int r = 0; r < 16; ++r)
      acc[r] = fmaf(Xs[(rg * 16 + r) * 128 + k], w, acc[r]);
  }
#pragma unroll
  for (int r = 0; r < 16; ++r) {
    long row = row0 + rg * 16 + r;
    if (row < n) H[row * 128 + col] = acc[r];
  }
}

// ---- alpha_s[n,h] = sum_c h[n,h,c]*a_src[h,c] ; same for alpha_d ----
__global__ __launch_bounds__(256) void k_alpha(const float* __restrict__ H,
                                               const float* __restrict__ a_src,
                                               const float* __restrict__ a_dst,
                                               float* __restrict__ as,
                                               float* __restrict__ ad, int n) {
  const int node = blockIdx.x * 2 + (threadIdx.x >> 7);
  const int c = threadIdx.x & 127;
  if (node >= n) return;
  float h = H[(long)node * 128 + c];
  float s = h * a_src[c];
  float d = h * a_dst[c];
#pragma unroll
  for (int off = 16; off > 0; off >>= 1) {
    s += __shfl_down(s, off, 32);
    d += __shfl_down(d, off, 32);
  }
  if ((c & 31) == 0) {
    as[node * 4 + (c >> 5)] = s;
    ad[node * 4 + (c >> 5)] = d;
  }
}

// ---- pass 1: segment max of leaky-relu logits over dst ----
__global__ __launch_bounds__(256) void k_edge_max(
    const int* __restrict__ ei, int E, int n, const float* __restrict__ as,
    const float* __restrict__ ad, unsigned* __restrict__ menc) {
  const int e = blockIdx.x * 256 + threadIdx.x;
  if (e >= E + n) return;
  int s, d;
  if (e < E) { s = ei[e]; d = ei[E + e]; } else { s = d = e - E; }
  float4 A = ((const float4*)as)[s];
  float4 B = ((const float4*)ad)[d];
  float l0 = A.x + B.x, l1 = A.y + B.y, l2 = A.z + B.z, l3 = A.w + B.w;
  l0 = l0 >= 0.f ? l0 : 0.2f * l0;
  l1 = l1 >= 0.f ? l1 : 0.2f * l1;
  l2 = l2 >= 0.f ? l2 : 0.2f * l2;
  l3 = l3 >= 0.f ? l3 : 0.2f * l3;
  atomicMax(&menc[d * 4 + 0], enc_f(l0));
  atomicMax(&menc[d * 4 + 1], enc_f(l1));
  atomicMax(&menc[d * 4 + 2], enc_f(l2));
  atomicMax(&menc[d * 4 + 3], enc_f(l3));
}

// ---- pass 2: e = exp(l - m[dst]); denom[dst] += e; store e per edge ----
__global__ __launch_bounds__(256) void k_edge_exp(
    const int* __restrict__ ei, int E, int n, const float* __restrict__ as,
    const float* __restrict__ ad, const unsigned* __restrict__ menc,
    float* __restrict__ ee, float* __restrict__ denom) {
  const int e = blockIdx.x * 256 + threadIdx.x;
  if (e >= E + n) return;
  int s, d;
  if (e < E) { s = ei[e]; d = ei[E + e]; } else { s = d = e - E; }
  float4 A = ((const float4*)as)[s];
  float4 B = ((const float4*)ad)[d];
  float l0 = A.x + B.x, l1 = A.y + B.y, l2 = A.z + B.z, l3 = A.w + B.w;
  l0 = l0 >= 0.f ? l0 : 0.2f * l0;
  l1 = l1 >= 0.f ? l1 : 0.2f * l1;
  l2 = l2 >= 0.f ? l2 : 0.2f * l2;
  l3 = l3 >= 0.f ? l3 : 0.2f * l3;
  float e0 = expf(l0 - dec_f(menc[d * 4 + 0]));
  float e1 = expf(l1 - dec_f(menc[d * 4 + 1]));
  float e2 = expf(l2 - dec_f(menc[d * 4 + 2]));
  float e3 = expf(l3 - dec_f(menc[d * 4 + 3]));
  ((float4*)ee)[e] = make_float4(e0, e1, e2, e3);
  atomicAdd(&denom[d * 4 + 0], e0);
  atomicAdd(&denom[d * 4 + 1], e1);
  atomicAdd(&denom[d * 4 + 2], e2);
  atomicAdd(&denom[d * 4 + 3], e3);
}

// ---- pass 3: out[dst] += alpha * h[src], 128 threads per edge ----
__global__ __launch_bounds__(256) void k_msg(const int* __restrict__ ei, int E,
                                             int n, const float* __restrict__ H,
                                             const float* __restrict__ ee,
                                             const float* __restrict__ denom,
                                             float* __restrict__ out) {
  const long e = (long)blockIdx.x * 2 + (threadIdx.x >> 7);
  if (e >= (long)E + n) return;
  const int c = threadIdx.x & 127, hd = c >> 5;
  int s, d;
  if (e < E) { s = ei[e]; d = ei[E + e]; } else { s = d = (int)(e - E); }
  float a = ee[e * 4 + hd] / (denom[d * 4 + hd] + 1e-16f);
  float v = a * H[(long)s * 128 + c];
  atomicAdd(&out[(long)d * 128 + c], v);
}

// ---- per-channel sum / sumsq over rows ----
__global__ __launch_bounds__(256) void k_stats(const float* __restrict__ V,
                                               float* __restrict__ stats,
                                               int n) {
  const int tid = threadIdx.x;
  const int c = tid & 127, half = tid >> 7;
  float s = 0.f, s2 = 0.f;
  for (int r = blockIdx.x * 2 + half; r < n; r += gridDim.x * 2) {
    float v = V[(long)r * 128 + c];
    s += v;
    s2 = fmaf(v, v, s2);
  }
  __shared__ float sh[256];
  sh[tid] = s;
  __syncthreads();
  if (half == 0) s += sh[tid + 128];
  __syncthreads();
  sh[tid] = s2;
  __syncthreads();
  if (half == 0) {
    s2 += sh[tid + 128];
    atomicAdd(&stats[c], s);
    atomicAdd(&stats[128 + c], s2);
  }
}

// ---- stats -> per-channel scale/shift (BN fold) ----
__global__ void k_finalize(const float* __restrict__ stats,
                           const float* __restrict__ gamma,
                           const float* __restrict__ beta,
                           float* __restrict__ ss, float invN) {
  int c = threadIdx.x;  // 128 threads
  float mean = stats[c] * invN;
  float var = stats[128 + c] * invN - mean * mean;
  float sc = gamma[c] * rsqrtf(var + 1e-5f);
  ss[c] = sc;
  ss[128 + c] = beta[c] - mean * sc;
}

// ---- y = relu(v*scale + shift [+ skip]) ----
__global__ __launch_bounds__(256) void k_bn_apply(
    const float* __restrict__ V, const float* __restrict__ ss,
    const float* __restrict__ skip, float* __restrict__ Y, int total4,
    int has_skip) {
  const int i = blockIdx.x * 256 + threadIdx.x;
  if (i >= total4) return;
  const int c4 = i & 31;
  float4 v = ((const float4*)V)[i];
  float4 sc = ((const float4*)ss)[c4];
  float4 sh = ((const float4*)ss)[32 + c4];
  float4 y;
  y.x = fmaf(v.x, sc.x, sh.x);
  y.y = fmaf(v.y, sc.y, sh.y);
  y.z = fmaf(v.z, sc.z, sh.z);
  y.w = fmaf(v.w, sc.w, sh.w);
  if (has_skip) {
    float4 s = ((const float4*)skip)[i];
    y.x += s.x; y.y += s.y; y.z += s.z; y.w += s.w;
  }
  y.x = fmaxf(y.x, 0.f);
  y.y = fmaxf(y.y, 0.f);
  y.z = fmaxf(y.z, 0.f);
  y.w = fmaxf(y.w, 0.f);
  ((float4*)Y)[i] = y;
}

static void run_gat_layer(const float* xin, const int* ei,
                          const float* W, const float* asrc, const float* adst,
                          const float* gamma, const float* beta,
                          const float* skip, int has_skip, float* yout,
                          float* A, float* Bagg, float* ee, float* as_,
                          float* ad_, unsigned* menc, float* denom,
                          float* stats, float* ss, int n, int E,
                          hipStream_t stream) {
  const size_t szNC = (size_t)n * 128 * sizeof(float);
  const int EP = E + n;
  hipMemsetAsync(Bagg, 0, szNC, stream);
  hipMemsetAsync(menc, 0, (size_t)n * 4 * sizeof(unsigned), stream);
  hipMemsetAsync(denom, 0, (size_t)n * 4 * sizeof(float), stream);
  hipMemsetAsync(stats, 0, 256 * sizeof(float), stream);

  k_gemm<<<(n + 31) / 32, 256, 0, stream>>>(xin, W, A, n);
  k_alpha<<<(n + 1) / 2, 256, 0, stream>>>(A, asrc, adst, as_, ad_, n);
  k_edge_max<<<(EP + 255) / 256, 256, 0, stream>>>(ei, E, n, as_, ad_, menc);
  k_edge_exp<<<(EP + 255) / 256, 256, 0, stream>>>(ei, E, n, as_, ad_, menc,
                                                   ee, denom);
  k_msg<<<(EP + 1) / 2, 256, 0, stream>>>(ei, E, n, A, ee, denom, Bagg);
  k_stats<<<256, 256, 0, stream>>>(Bagg, stats, n);
  k_finalize<<<1, 128, 0, stream>>>(stats, gamma, beta, ss, 1.0f / (float)n);
  k_bn_apply<<<(n * 32 + 255) / 256, 256, 0, stream>>>(Bagg, ss, skip, yout,
                                                       n * 32, has_skip);
}

extern "C" void kernel_launch(void* const* d_in, const int* in_sizes, int n_in,
                              void* d_out, int out_size, void* d_ws,
                              size_t ws_size, hipStream_t stream) {
  const float* x = (const float*)d_in[0];
  const int* ei = (const int*)d_in[1];
  const float* W1 = (const float*)d_in[2];
  const float* a_src1 = (const float*)d_in[3];
  const float* a_dst1 = (const float*)d_in[4];
  // d_in[5] = b1 : cancels in batch-norm, unused
  const float* gamma1 = (const float*)d_in[6];
  const float* beta1 = (const float*)d_in[7];
  const float* W2 = (const float*)d_in[8];
  const float* a_src2 = (const float*)d_in[9];
  const float* a_dst2 = (const float*)d_in[10];
  // d_in[11] = b2 : unused
  const float* gamma2 = (const float*)d_in[12];
  const float* beta2 = (const float*)d_in[13];

  const int n = in_sizes[0] / 128;
  const int E = in_sizes[1] / 2;
  const int EP = E + n;

  char* w = (char*)d_ws;
  const size_t szNC = (size_t)n * 128 * sizeof(float);
  float* A = (float*)w;            w += szNC;                       // h buffer
  float* Bagg = (float*)w;         w += szNC;                       // aggregation
  float* ee = (float*)w;           w += (size_t)EP * 4 * sizeof(float);
  float* as_ = (float*)w;          w += (size_t)n * 4 * sizeof(float);
  float* ad_ = (float*)w;          w += (size_t)n * 4 * sizeof(float);
  unsigned* menc = (unsigned*)w;   w += (size_t)n * 4 * sizeof(unsigned);
  float* denom = (float*)w;        w += (size_t)n * 4 * sizeof(float);
  float* stats = (float*)w;        w += 256 * sizeof(float);
  float* ss = (float*)w;           w += 256 * sizeof(float);

  float* y1 = (float*)d_out;  // park layer-1 activation in d_out

  // layer 1: y1 = relu(bn(gat(x)))
  run_gat_layer(x, ei, W1, a_src1, a_dst1, gamma1, beta1, nullptr, 0, y1, A,
                Bagg, ee, as_, ad_, menc, denom, stats, ss, n, E, stream);
  // layer 2: out = relu(bn(gat(y1)) + x)
  run_gat_layer(y1, ei, W2, a_src2, a_dst2, gamma2, beta2, x, 1,
                (float*)d_out, A, Bagg, ee, as_, ad_, menc, denom, stats, ss,
                n, E, stream);
}

// Round 2
// 1364.544 us; speedup vs baseline: 2.3363x; 2.3363x over previous
//
#include <hip/hip_runtime.h>

// ---------------- GEMM: H = X[n,128] @ W[128,128], fused alpha dots ----------
// block = 256 thr: colg = tid&31 (4 cols each -> 128 cols), rowg = tid>>5
// (4 rows each -> 32 rows/block). 4x4 register tile, k chunked by 4 (float4).
// Optional fused input transform: x = relu(x*sc+sh)  (folds layer-1 BN+ReLU).
// Epilogue: alpha_s/alpha_d per (row, head) via 8-lane shuffle reduce.
__global__ __launch_bounds__(256) void k_gemm(
    const float* __restrict__ X, const float* __restrict__ W,
    float* __restrict__ H, int n, const float* __restrict__ bnss,
    const float* __restrict__ a_src, const float* __restrict__ a_dst,
    float* __restrict__ as_, float* __restrict__ ad_) {
  __shared__ float Ws[128 * 128];  // [k][col], 64 KB
  __shared__ float Xs[32 * 128];   // [row][k], 16 KB
  const int tid = threadIdx.x;
  for (int i = tid; i < 4096; i += 256)
    ((float4*)Ws)[i] = ((const float4*)W)[i];
  const long row0 = (long)blockIdx.x * 32;
  for (int i = tid; i < 1024; i += 256) {
    long r = row0 + (i >> 5);
    if (r >= n) r = n - 1;
    float4 v = ((const float4*)X)[r * 32 + (i & 31)];
    if (bnss) {
      const int cg = i & 31;
      float4 sc = ((const float4*)bnss)[cg];
      float4 sh = ((const float4*)bnss)[32 + cg];
      v.x = fmaxf(fmaf(v.x, sc.x, sh.x), 0.f);
      v.y = fmaxf(fmaf(v.y, sc.y, sh.y), 0.f);
      v.z = fmaxf(fmaf(v.z, sc.z, sh.z), 0.f);
      v.w = fmaxf(fmaf(v.w, sc.w, sh.w), 0.f);
    }
    ((float4*)Xs)[i] = v;
  }
  __syncthreads();
  const int colg = tid & 31;   // cols colg*4..+3
  const int rowg = tid >> 5;   // rows rowg*4..+3
  float acc[4][4];
#pragma unroll
  for (int r = 0; r < 4; ++r)
#pragma unroll
    for (int c = 0; c < 4; ++c) acc[r][c] = 0.f;

  for (int k = 0; k < 128; k += 4) {
    float4 w[4];
#pragma unroll
    for (int kk = 0; kk < 4; ++kk)
      w[kk] = *(const float4*)&Ws[(k + kk) * 128 + colg * 4];
#pragma unroll
    for (int r = 0; r < 4; ++r) {
      float4 x4 = *(const float4*)&Xs[(rowg * 4 + r) * 128 + k];
      acc[r][0] = fmaf(x4.x, w[0].x, acc[r][0]);
      acc[r][1] = fmaf(x4.x, w[0].y, acc[r][1]);
      acc[r][2] = fmaf(x4.x, w[0].z, acc[r][2]);
      acc[r][3] = fmaf(x4.x, w[0].w, acc[r][3]);
      acc[r][0] = fmaf(x4.y, w[1].x, acc[r][0]);
      acc[r][1] = fmaf(x4.y, w[1].y, acc[r][1]);
      acc[r][2] = fmaf(x4.y, w[1].z, acc[r][2]);
      acc[r][3] = fmaf(x4.y, w[1].w, acc[r][3]);
      acc[r][0] = fmaf(x4.z, w[2].x, acc[r][0]);
      acc[r][1] = fmaf(x4.z, w[2].y, acc[r][1]);
      acc[r][2] = fmaf(x4.z, w[2].z, acc[r][2]);
      acc[r][3] = fmaf(x4.z, w[2].w, acc[r][3]);
      acc[r][0] = fmaf(x4.w, w[3].x, acc[r][0]);
      acc[r][1] = fmaf(x4.w, w[3].y, acc[r][1]);
      acc[r][2] = fmaf(x4.w, w[3].z, acc[r][2]);
      acc[r][3] = fmaf(x4.w, w[3].w, acc[r][3]);
    }
  }

  const float4 asv = ((const float4*)a_src)[colg];
  const float4 adv = ((const float4*)a_dst)[colg];
  const int hd = colg >> 3;
#pragma unroll
  for (int r = 0; r < 4; ++r) {
    const long row = row0 + rowg * 4 + r;
    if (row < n)
      *(float4*)&H[row * 128 + colg * 4] =
          make_float4(acc[r][0], acc[r][1], acc[r][2], acc[r][3]);
    float sp = acc[r][0] * asv.x + acc[r][1] * asv.y + acc[r][2] * asv.z +
               acc[r][3] * asv.w;
    float dp = acc[r][0] * adv.x + acc[r][1] * adv.y + acc[r][2] * adv.z +
               acc[r][3] * adv.w;
#pragma unroll
    for (int off = 4; off > 0; off >>= 1) {
      sp += __shfl_down(sp, off, 8);
      dp += __shfl_down(dp, off, 8);
    }
    if ((colg & 7) == 0 && row < n) {
      as_[row * 4 + hd] = sp;
      ad_[row * 4 + hd] = dp;
    }
  }
}

// ---------------- CSR build -------------------------------------------------
__global__ __launch_bounds__(256) void k_count(const int* __restrict__ ei,
                                               int E, int* __restrict__ deg) {
  const int e = blockIdx.x * 256 + threadIdx.x;
  if (e < E) atomicAdd(&deg[ei[E + e]], 1);
}

__global__ __launch_bounds__(256) void k_scan1(const int* __restrict__ deg,
                                               int n, int* __restrict__ bsum) {
  __shared__ int sh[256];
  const int i = blockIdx.x * 256 + threadIdx.x;
  sh[threadIdx.x] = (i < n) ? deg[i] + 1 : 0;
  __syncthreads();
  for (int off = 128; off > 0; off >>= 1) {
    if (threadIdx.x < off) sh[threadIdx.x] += sh[threadIdx.x + off];
    __syncthreads();
  }
  if (threadIdx.x == 0) bsum[blockIdx.x] = sh[0];
}

__global__ void k_scan2(int* __restrict__ bsum, int nb) {
  if (threadIdx.x == 0) {
    int run = 0;
    for (int b = 0; b < nb; ++b) {
      int t = bsum[b];
      bsum[b] = run;
      run += t;
    }
  }
}

__global__ __launch_bounds__(256) void k_scan3(const int* __restrict__ deg,
                                               int n,
                                               const int* __restrict__ bsum,
                                               int* __restrict__ offs,
                                               int* __restrict__ cursor) {
  __shared__ int sh[256];
  const int i = blockIdx.x * 256 + threadIdx.x;
  const int v = (i < n) ? deg[i] + 1 : 0;
  sh[threadIdx.x] = v;
  __syncthreads();
  for (int off = 1; off < 256; off <<= 1) {
    int t = (threadIdx.x >= off) ? sh[threadIdx.x - off] : 0;
    __syncthreads();
    sh[threadIdx.x] += t;
    __syncthreads();
  }
  if (i < n) {
    int o = bsum[blockIdx.x] + sh[threadIdx.x] - v;  // exclusive
    offs[i] = o;
    cursor[i] = o;
  }
}

__global__ __launch_bounds__(256) void k_fill(const int* __restrict__ ei,
                                              int E, int n,
                                              int* __restrict__ cursor,
                                              int* __restrict__ srcs) {
  const int e = blockIdx.x * 256 + threadIdx.x;
  if (e >= E + n) return;
  int s, d;
  if (e < E) {
    s = ei[e];
    d = ei[E + e];
  } else {
    s = d = e - E;
  }
  const int pos = atomicAdd(&cursor[d], 1);
  srcs[pos] = s;
}

// ---------------- fused GAT aggregation (per dst node, no atomics) ----------
// 128 threads/node (2 nodes per 256-block). thread c: head hd=c>>5, lane=c&31.
// A: 32-lane strided max over edges; B: strided exp-sum; C: per-channel
// accumulate over edges with recomputed alpha, one coalesced 512B store.
__global__ __launch_bounds__(256) void k_agg(
    const int* __restrict__ offs, const int* __restrict__ deg,
    const int* __restrict__ srcs, const float* __restrict__ H,
    const float* __restrict__ as_, const float* __restrict__ ad_,
    float* __restrict__ out, int n) {
  const int node = blockIdx.x * 2 + (threadIdx.x >> 7);
  if (node >= n) return;
  const int c = threadIdx.x & 127;
  const int hd = c >> 5, lane = c & 31;
  const int o0 = offs[node];
  const int dg = deg[node] + 1;  // + self-loop
  const float adv = ad_[node * 4 + hd];

  float mx = -INFINITY;
  for (int j = lane; j < dg; j += 32) {
    const int s = srcs[o0 + j];
    float l = as_[s * 4 + hd] + adv;
    l = l >= 0.f ? l : 0.2f * l;
    mx = fmaxf(mx, l);
  }
#pragma unroll
  for (int off = 16; off > 0; off >>= 1)
    mx = fmaxf(mx, __shfl_down(mx, off, 32));
  mx = __shfl(mx, 0, 32);

  float sm = 0.f;
  for (int j = lane; j < dg; j += 32) {
    const int s = srcs[o0 + j];
    float l = as_[s * 4 + hd] + adv;
    l = l >= 0.f ? l : 0.2f * l;
    sm += __expf(l - mx);
  }
#pragma unroll
  for (int off = 16; off > 0; off >>= 1) sm += __shfl_down(sm, off, 32);
  sm = __shfl(sm, 0, 32);
  const float invden = 1.f / (sm + 1e-16f);

  float acc = 0.f;
  for (int j = 0; j < dg; ++j) {
    const int s = srcs[o0 + j];
    float l = as_[s * 4 + hd] + adv;
    l = l >= 0.f ? l : 0.2f * l;
    const float w = __expf(l - mx) * invden;
    acc = fmaf(w, H[(long)s * 128 + c], acc);
  }
  out[(long)node * 128 + c] = acc;
}

// ---------------- BN stats / fold / apply -----------------------------------
__global__ __launch_bounds__(256) void k_stats(const float* __restrict__ V,
                                               float* __restrict__ stats,
                                               int n) {
  const int tid = threadIdx.x;
  const int c = tid & 127, half = tid >> 7;
  float s = 0.f, s2 = 0.f;
  for (int r = blockIdx.x * 2 + half; r < n; r += gridDim.x * 2) {
    float v = V[(long)r * 128 + c];
    s += v;
    s2 = fmaf(v, v, s2);
  }
  __shared__ float sh[256];
  sh[tid] = s;
  __syncthreads();
  if (half == 0) s += sh[tid + 128];
  __syncthreads();
  sh[tid] = s2;
  __syncthreads();
  if (half == 0) {
    s2 += sh[tid + 128];
    atomicAdd(&stats[c], s);
    atomicAdd(&stats[128 + c], s2);
  }
}

__global__ void k_finalize(const float* __restrict__ stats,
                           const float* __restrict__ gamma,
                           const float* __restrict__ beta,
                           float* __restrict__ ss, float invN) {
  int c = threadIdx.x;  // 128 threads
  float mean = stats[c] * invN;
  float var = stats[128 + c] * invN - mean * mean;
  float sc = gamma[c] * rsqrtf(var + 1e-5f);
  ss[c] = sc;
  ss[128 + c] = beta[c] - mean * sc;
}

__global__ __launch_bounds__(256) void k_bn_apply(
    const float* __restrict__ V, const float* __restrict__ ss,
    const float* __restrict__ skip, float* __restrict__ Y, int total4) {
  const int i = blockIdx.x * 256 + threadIdx.x;
  if (i >= total4) return;
  const int c4 = i & 31;
  float4 v = ((const float4*)V)[i];
  float4 sc = ((const float4*)ss)[c4];
  float4 sh = ((const float4*)ss)[32 + c4];
  float4 s = ((const float4*)skip)[i];
  float4 y;
  y.x = fmaxf(fmaf(v.x, sc.x, sh.x) + s.x, 0.f);
  y.y = fmaxf(fmaf(v.y, sc.y, sh.y) + s.y, 0.f);
  y.z = fmaxf(fmaf(v.z, sc.z, sh.z) + s.z, 0.f);
  y.w = fmaxf(fmaf(v.w, sc.w, sh.w) + s.w, 0.f);
  ((float4*)Y)[i] = y;
}

extern "C" void kernel_launch(void* const* d_in, const int* in_sizes, int n_in,
                              void* d_out, int out_size, void* d_ws,
                              size_t ws_size, hipStream_t stream) {
  const float* x = (const float*)d_in[0];
  const int* ei = (const int*)d_in[1];
  const float* W1 = (const float*)d_in[2];
  const float* a_src1 = (const float*)d_in[3];
  const float* a_dst1 = (const float*)d_in[4];
  // b1 cancels in BN
  const float* gamma1 = (const float*)d_in[6];
  const float* beta1 = (const float*)d_in[7];
  const float* W2 = (const float*)d_in[8];
  const float* a_src2 = (const float*)d_in[9];
  const float* a_dst2 = (const float*)d_in[10];
  // b2 cancels in BN
  const float* gamma2 = (const float*)d_in[12];
  const float* beta2 = (const float*)d_in[13];

  const int n = in_sizes[0] / 128;
  const int E = in_sizes[1] / 2;
  const int EP = E + n;
  const int nb = (n + 255) / 256;

  char* w = (char*)d_ws;
  const size_t szNC = (size_t)n * 128 * sizeof(float);
  float* H = (float*)w;    w += szNC;
  float* Bagg = (float*)w; w += szNC;
  float* as_ = (float*)w;  w += (size_t)n * 4 * sizeof(float);
  float* ad_ = (float*)w;  w += (size_t)n * 4 * sizeof(float);
  int* srcs = (int*)w;     w += (size_t)EP * sizeof(int);
  int* deg = (int*)w;      w += (size_t)n * sizeof(int);
  int* offs = (int*)w;     w += (size_t)n * sizeof(int);
  int* cursor = (int*)w;   w += (size_t)n * sizeof(int);
  int* bsum = (int*)w;     w += (size_t)nb * sizeof(int);
  float* stats = (float*)w; w += 256 * sizeof(float);
  float* ss1 = (float*)w;  w += 256 * sizeof(float);
  float* ss2 = (float*)w;  w += 256 * sizeof(float);

  // ---- CSR build (shared by both layers) ----
  hipMemsetAsync(deg, 0, (size_t)n * sizeof(int), stream);
  k_count<<<(E + 255) / 256, 256, 0, stream>>>(ei, E, deg);
  k_scan1<<<nb, 256, 0, stream>>>(deg, n, bsum);
  k_scan2<<<1, 64, 0, stream>>>(bsum, nb);
  k_scan3<<<nb, 256, 0, stream>>>(deg, n, bsum, offs, cursor);
  k_fill<<<(EP + 255) / 256, 256, 0, stream>>>(ei, E, n, cursor, srcs);

  // ---- layer 1 ----
  k_gemm<<<(n + 31) / 32, 256, 0, stream>>>(x, W1, H, n, nullptr, a_src1,
                                            a_dst1, as_, ad_);
  k_agg<<<(n + 1) / 2, 256, 0, stream>>>(offs, deg, srcs, H, as_, ad_, Bagg,
                                         n);
  hipMemsetAsync(stats, 0, 256 * sizeof(float), stream);
  k_stats<<<256, 256, 0, stream>>>(Bagg, stats, n);
  k_finalize<<<1, 128, 0, stream>>>(stats, gamma1, beta1, ss1,
                                    1.0f / (float)n);

  // ---- layer 2 (BN1+ReLU folded into GEMM2's X load; y1 never stored) ----
  k_gemm<<<(n + 31) / 32, 256, 0, stream>>>(Bagg, W2, H, n, ss1, a_src2,
                                            a_dst2, as_, ad_);
  k_agg<<<(n + 1) / 2, 256, 0, stream>>>(offs, deg, srcs, H, as_, ad_, Bagg,
                                         n);
  hipMemsetAsync(stats, 0, 256 * sizeof(float), stream);
  k_stats<<<256, 256, 0, stream>>>(Bagg, stats, n);
  k_finalize<<<1, 128, 0, stream>>>(stats, gamma2, beta2, ss2,
                                    1.0f / (float)n);
  k_bn_apply<<<(n * 32 + 255) / 256, 256, 0, stream>>>(Bagg, ss2, x,
                                                       (float*)d_out, n * 32);
}

// Round 3
// 793.262 us; speedup vs baseline: 4.0189x; 1.7202x over previous
//
#include <hip/hip_runtime.h>

// pack two fp32 -> two bf16 (RNE) in one uint (a = low = even channel)
__device__ __forceinline__ unsigned pack_bf16x2(float a, float b) {
  unsigned ua = __float_as_uint(a);
  ua = (ua + 0x7fffu + ((ua >> 16) & 1u)) >> 16;
  unsigned ub = __float_as_uint(b);
  ub = (ub + 0x7fffu + ((ub >> 16) & 1u)) >> 16;
  return ua | (ub << 16);
}

// ---------------- GEMM: H(bf16) = X[n,128] @ W[128,128], fused alpha dots ---
// block = 256 thr: colg = tid&31 (4 cols each), rowg = tid>>5 (4 rows each,
// 32 rows/block). Optional fused input transform x = relu(x*sc+sh) folds the
// previous layer's BN+ReLU. Epilogue also emits alpha_s/alpha_d (fp32 accs).
__global__ __launch_bounds__(256) void k_gemm(
    const float* __restrict__ X, const float* __restrict__ W,
    unsigned* __restrict__ Hb, int n, const float* __restrict__ bnss,
    const float* __restrict__ a_src, const float* __restrict__ a_dst,
    float* __restrict__ as_, float* __restrict__ ad_) {
  __shared__ float Ws[128 * 128];  // [k][col], 64 KB
  __shared__ float Xs[32 * 128];   // [row][k], 16 KB
  const int tid = threadIdx.x;
  for (int i = tid; i < 4096; i += 256)
    ((float4*)Ws)[i] = ((const float4*)W)[i];
  const long row0 = (long)blockIdx.x * 32;
  for (int i = tid; i < 1024; i += 256) {
    long r = row0 + (i >> 5);
    if (r >= n) r = n - 1;
    float4 v = ((const float4*)X)[r * 32 + (i & 31)];
    if (bnss) {
      const int cg = i & 31;
      float4 sc = ((const float4*)bnss)[cg];
      float4 sh = ((const float4*)bnss)[32 + cg];
      v.x = fmaxf(fmaf(v.x, sc.x, sh.x), 0.f);
      v.y = fmaxf(fmaf(v.y, sc.y, sh.y), 0.f);
      v.z = fmaxf(fmaf(v.z, sc.z, sh.z), 0.f);
      v.w = fmaxf(fmaf(v.w, sc.w, sh.w), 0.f);
    }
    ((float4*)Xs)[i] = v;
  }
  __syncthreads();
  const int colg = tid & 31;
  const int rowg = tid >> 5;
  float acc[4][4];
#pragma unroll
  for (int r = 0; r < 4; ++r)
#pragma unroll
    for (int c = 0; c < 4; ++c) acc[r][c] = 0.f;

  for (int k = 0; k < 128; k += 4) {
    float4 w[4];
#pragma unroll
    for (int kk = 0; kk < 4; ++kk)
      w[kk] = *(const float4*)&Ws[(k + kk) * 128 + colg * 4];
#pragma unroll
    for (int r = 0; r < 4; ++r) {
      float4 x4 = *(const float4*)&Xs[(rowg * 4 + r) * 128 + k];
      acc[r][0] = fmaf(x4.x, w[0].x, acc[r][0]);
      acc[r][1] = fmaf(x4.x, w[0].y, acc[r][1]);
      acc[r][2] = fmaf(x4.x, w[0].z, acc[r][2]);
      acc[r][3] = fmaf(x4.x, w[0].w, acc[r][3]);
      acc[r][0] = fmaf(x4.y, w[1].x, acc[r][0]);
      acc[r][1] = fmaf(x4.y, w[1].y, acc[r][1]);
      acc[r][2] = fmaf(x4.y, w[1].z, acc[r][2]);
      acc[r][3] = fmaf(x4.y, w[1].w, acc[r][3]);
      acc[r][0] = fmaf(x4.z, w[2].x, acc[r][0]);
      acc[r][1] = fmaf(x4.z, w[2].y, acc[r][1]);
      acc[r][2] = fmaf(x4.z, w[2].z, acc[r][2]);
      acc[r][3] = fmaf(x4.z, w[2].w, acc[r][3]);
      acc[r][0] = fmaf(x4.w, w[3].x, acc[r][0]);
      acc[r][1] = fmaf(x4.w, w[3].y, acc[r][1]);
      acc[r][2] = fmaf(x4.w, w[3].z, acc[r][2]);
      acc[r][3] = fmaf(x4.w, w[3].w, acc[r][3]);
    }
  }

  const float4 asv = ((const float4*)a_src)[colg];
  const float4 adv = ((const float4*)a_dst)[colg];
  const int hd = colg >> 3;
#pragma unroll
  for (int r = 0; r < 4; ++r) {
    const long row = row0 + rowg * 4 + r;
    if (row < n) {
      uint2 p;
      p.x = pack_bf16x2(acc[r][0], acc[r][1]);
      p.y = pack_bf16x2(acc[r][2], acc[r][3]);
      ((uint2*)Hb)[row * 32 + colg] = p;
    }
    float sp = acc[r][0] * asv.x + acc[r][1] * asv.y + acc[r][2] * asv.z +
               acc[r][3] * asv.w;
    float dp = acc[r][0] * adv.x + acc[r][1] * adv.y + acc[r][2] * adv.z +
               acc[r][3] * adv.w;
#pragma unroll
    for (int off = 4; off > 0; off >>= 1) {
      sp += __shfl_down(sp, off, 8);
      dp += __shfl_down(dp, off, 8);
    }
    if ((colg & 7) == 0 && row < n) {
      as_[row * 4 + hd] = sp;
      ad_[row * 4 + hd] = dp;
    }
  }
}

// ---------------- CSR build -------------------------------------------------
__global__ __launch_bounds__(256) void k_count(const int* __restrict__ ei,
                                               int E, int* __restrict__ deg) {
  const int e = blockIdx.x * 256 + threadIdx.x;
  if (e < E) atomicAdd(&deg[ei[E + e]], 1);
}

__global__ __launch_bounds__(256) void k_scan1(const int* __restrict__ deg,
                                               int n, int* __restrict__ bsum) {
  __shared__ int sh[256];
  const int i = blockIdx.x * 256 + threadIdx.x;
  sh[threadIdx.x] = (i < n) ? deg[i] + 1 : 0;
  __syncthreads();
  for (int off = 128; off > 0; off >>= 1) {
    if (threadIdx.x < off) sh[threadIdx.x] += sh[threadIdx.x + off];
    __syncthreads();
  }
  if (threadIdx.x == 0) bsum[blockIdx.x] = sh[0];
}

__global__ void k_scan2(int* __restrict__ bsum, int nb) {
  if (threadIdx.x == 0) {
    int run = 0;
    for (int b = 0; b < nb; ++b) {
      int t = bsum[b];
      bsum[b] = run;
      run += t;
    }
  }
}

__global__ __launch_bounds__(256) void k_scan3(const int* __restrict__ deg,
                                               int n,
                                               const int* __restrict__ bsum,
                                               int* __restrict__ offs,
                                               int* __restrict__ cursor) {
  __shared__ int sh[256];
  const int i = blockIdx.x * 256 + threadIdx.x;
  const int v = (i < n) ? deg[i] + 1 : 0;
  sh[threadIdx.x] = v;
  __syncthreads();
  for (int off = 1; off < 256; off <<= 1) {
    int t = (threadIdx.x >= off) ? sh[threadIdx.x - off] : 0;
    __syncthreads();
    sh[threadIdx.x] += t;
    __syncthreads();
  }
  if (i < n) {
    int o = bsum[blockIdx.x] + sh[threadIdx.x] - v;  // exclusive
    offs[i] = o;
    cursor[i] = o;
  }
}

__global__ __launch_bounds__(256) void k_fill(const int* __restrict__ ei,
                                              int E, int n,
                                              int* __restrict__ cursor,
                                              int* __restrict__ srcs) {
  const int e = blockIdx.x * 256 + threadIdx.x;
  if (e >= E + n) return;
  int s, d;
  if (e < E) {
    s = ei[e];
    d = ei[E + e];
  } else {
    s = d = e - E;
  }
  const int pos = atomicAdd(&cursor[d], 1);
  srcs[pos] = s;
}

// ---------------- fused GAT aggregation: single pass, no atomics ------------
// 64 threads per node (4 nodes / 256-block). Thread t owns channels 2t,2t+1
// (head th = t>>4). Edges processed in chunks of 16: lane t computes the
// softmax weight e=exp(l) for edge (base + (t&15)), head t>>4 (no max pass:
// |logit| is O(1), exp can't overflow); inner loop broadcasts src index and
// weight via shuffles and gathers bf16 H rows (one dword per thread).
// out = (sum e*h) / (sum e)  -- normalization deferred to the end.
__global__ __launch_bounds__(256) void k_agg(
    const int* __restrict__ offs, const int* __restrict__ deg,
    const int* __restrict__ srcs, const unsigned* __restrict__ Hb,
    const float* __restrict__ as_, const float* __restrict__ ad_,
    float* __restrict__ out, int n) {
  const int node = blockIdx.x * 4 + (threadIdx.x >> 6);
  if (node >= n) return;
  const int t = threadIdx.x & 63;
  const int th = t >> 4;     // head of my channels
  const int j16 = t & 15;    // my edge slot in each chunk
  const int o0 = offs[node];
  const int dg = deg[node] + 1;  // + self-loop
  const float adv = ad_[node * 4 + th];

  float den = 0.f;
  float2 acc = make_float2(0.f, 0.f);

  for (int base = 0; base < dg; base += 16) {
    const int j = base + j16;
    int s = 0;
    float e = 0.f;
    if (j < dg) {
      s = srcs[o0 + j];
      float l = as_[s * 4 + th] + adv;
      l = l >= 0.f ? l : 0.2f * l;
      e = __expf(fminf(l, 80.f));
    }
    den += e;
#pragma unroll
    for (int jj = 0; jj < 16; ++jj) {
      const int ss = __shfl(s, jj, 64);
      const float w = __shfl(e, (t & 48) | jj, 64);
      const unsigned hv = Hb[(long)ss * 64 + t];
      acc.x = fmaf(w, __uint_as_float(hv << 16), acc.x);
      acc.y = fmaf(w, __uint_as_float(hv & 0xffff0000u), acc.y);
    }
  }
  // reduce den within the 16-lane head group
#pragma unroll
  for (int off = 8; off > 0; off >>= 1) den += __shfl_xor(den, off, 64);
  const float invden = 1.f / (den + 1e-16f);
  acc.x *= invden;
  acc.y *= invden;
  ((float2*)out)[(long)node * 64 + t] = acc;
}

// ---------------- BN stats / fold / apply -----------------------------------
__global__ __launch_bounds__(256) void k_stats(const float* __restrict__ V,
                                               float* __restrict__ stats,
                                               int n) {
  const int tid = threadIdx.x;
  const int c = tid & 127, half = tid >> 7;
  float s = 0.f, s2 = 0.f;
  for (int r = blockIdx.x * 2 + half; r < n; r += gridDim.x * 2) {
    float v = V[(long)r * 128 + c];
    s += v;
    s2 = fmaf(v, v, s2);
  }
  __shared__ float sh[256];
  sh[tid] = s;
  __syncthreads();
  if (half == 0) s += sh[tid + 128];
  __syncthreads();
  sh[tid] = s2;
  __syncthreads();
  if (half == 0) {
    s2 += sh[tid + 128];
    atomicAdd(&stats[c], s);
    atomicAdd(&stats[128 + c], s2);
  }
}

__global__ void k_finalize(const float* __restrict__ stats,
                           const float* __restrict__ gamma,
                           const float* __restrict__ beta,
                           float* __restrict__ ss, float invN) {
  int c = threadIdx.x;  // 128 threads
  float mean = stats[c] * invN;
  float var = stats[128 + c] * invN - mean * mean;
  float sc = gamma[c] * rsqrtf(var + 1e-5f);
  ss[c] = sc;
  ss[128 + c] = beta[c] - mean * sc;
}

__global__ __launch_bounds__(256) void k_bn_apply(
    const float* __restrict__ V, const float* __restrict__ ss,
    const float* __restrict__ skip, float* __restrict__ Y, int total4) {
  const int i = blockIdx.x * 256 + threadIdx.x;
  if (i >= total4) return;
  const int c4 = i & 31;
  float4 v = ((const float4*)V)[i];
  float4 sc = ((const float4*)ss)[c4];
  float4 sh = ((const float4*)ss)[32 + c4];
  float4 s = ((const float4*)skip)[i];
  float4 y;
  y.x = fmaxf(fmaf(v.x, sc.x, sh.x) + s.x, 0.f);
  y.y = fmaxf(fmaf(v.y, sc.y, sh.y) + s.y, 0.f);
  y.z = fmaxf(fmaf(v.z, sc.z, sh.z) + s.z, 0.f);
  y.w = fmaxf(fmaf(v.w, sc.w, sh.w) + s.w, 0.f);
  ((float4*)Y)[i] = y;
}

extern "C" void kernel_launch(void* const* d_in, const int* in_sizes, int n_in,
                              void* d_out, int out_size, void* d_ws,
                              size_t ws_size, hipStream_t stream) {
  const float* x = (const float*)d_in[0];
  const int* ei = (const int*)d_in[1];
  const float* W1 = (const float*)d_in[2];
  const float* a_src1 = (const float*)d_in[3];
  const float* a_dst1 = (const float*)d_in[4];
  // b1 cancels in BN
  const float* gamma1 = (const float*)d_in[6];
  const float* beta1 = (const float*)d_in[7];
  const float* W2 = (const float*)d_in[8];
  const float* a_src2 = (const float*)d_in[9];
  const float* a_dst2 = (const float*)d_in[10];
  // b2 cancels in BN
  const float* gamma2 = (const float*)d_in[12];
  const float* beta2 = (const float*)d_in[13];

  const int n = in_sizes[0] / 128;
  const int E = in_sizes[1] / 2;
  const int EP = E + n;
  const int nb = (n + 255) / 256;

  char* w = (char*)d_ws;
  const size_t szNC = (size_t)n * 128 * sizeof(float);
  unsigned* Hb = (unsigned*)w;  w += (size_t)n * 64 * sizeof(unsigned);  // bf16 H
  float* Bagg = (float*)w;      w += szNC;
  float* as_ = (float*)w;       w += (size_t)n * 4 * sizeof(float);
  float* ad_ = (float*)w;       w += (size_t)n * 4 * sizeof(float);
  int* srcs = (int*)w;          w += (size_t)EP * sizeof(int);
  int* deg = (int*)w;           w += (size_t)n * sizeof(int);
  int* offs = (int*)w;          w += (size_t)n * sizeof(int);
  int* cursor = (int*)w;        w += (size_t)n * sizeof(int);
  int* bsum = (int*)w;          w += (size_t)nb * sizeof(int);
  float* stats = (float*)w;     w += 256 * sizeof(float);
  float* ss1 = (float*)w;       w += 256 * sizeof(float);
  float* ss2 = (float*)w;       w += 256 * sizeof(float);

  // ---- CSR build (shared by both layers) ----
  hipMemsetAsync(deg, 0, (size_t)n * sizeof(int), stream);
  k_count<<<(E + 255) / 256, 256, 0, stream>>>(ei, E, deg);
  k_scan1<<<nb, 256, 0, stream>>>(deg, n, bsum);
  k_scan2<<<1, 64, 0, stream>>>(bsum, nb);
  k_scan3<<<nb, 256, 0, stream>>>(deg, n, bsum, offs, cursor);
  k_fill<<<(EP + 255) / 256, 256, 0, stream>>>(ei, E, n, cursor, srcs);

  // ---- layer 1 ----
  k_gemm<<<(n + 31) / 32, 256, 0, stream>>>(x, W1, Hb, n, nullptr, a_src1,
                                            a_dst1, as_, ad_);
  k_agg<<<(n + 3) / 4, 256, 0, stream>>>(offs, deg, srcs, Hb, as_, ad_, Bagg,
                                         n);
  hipMemsetAsync(stats, 0, 256 * sizeof(float), stream);
  k_stats<<<256, 256, 0, stream>>>(Bagg, stats, n);
  k_finalize<<<1, 128, 0, stream>>>(stats, gamma1, beta1, ss1,
                                    1.0f / (float)n);

  // ---- layer 2 (BN1+ReLU folded into GEMM2's X load; y1 never stored) ----
  k_gemm<<<(n + 31) / 32, 256, 0, stream>>>(Bagg, W2, Hb, n, ss1, a_src2,
                                            a_dst2, as_, ad_);
  k_agg<<<(n + 3) / 4, 256, 0, stream>>>(offs, deg, srcs, Hb, as_, ad_, Bagg,
                                         n);
  hipMemsetAsync(stats, 0, 256 * sizeof(float), stream);
  k_stats<<<256, 256, 0, stream>>>(Bagg, stats, n);
  k_finalize<<<1, 128, 0, stream>>>(stats, gamma2, beta2, ss2,
                                    1.0f / (float)n);
  k_bn_apply<<<(n * 32 + 255) / 256, 256, 0, stream>>>(Bagg, ss2, x,
                                                       (float*)d_out, n * 32);
}

// Round 4
// 632.730 us; speedup vs baseline: 5.0385x; 1.2537x over previous
//
#include <hip/hip_runtime.h>

#define MAXNB 1024  // max dst-buckets (128 nodes each) -> supports n <= 131072

// pack two fp32 -> two bf16 (RNE) in one uint (a = low = even channel)
__device__ __forceinline__ unsigned pack_bf16x2(float a, float b) {
  unsigned ua = __float_as_uint(a);
  ua = (ua + 0x7fffu + ((ua >> 16) & 1u)) >> 16;
  unsigned ub = __float_as_uint(b);
  ub = (ub + 0x7fffu + ((ub >> 16) & 1u)) >> 16;
  return ua | (ub << 16);
}

// ---------------- GEMM: H(bf16) = X[n,128] @ W[128,128], fused alpha dots ---
__global__ __launch_bounds__(256) void k_gemm(
    const float* __restrict__ X, const float* __restrict__ W,
    unsigned* __restrict__ Hb, int n, const float* __restrict__ bnss,
    const float* __restrict__ a_src, const float* __restrict__ a_dst,
    float* __restrict__ as_, float* __restrict__ ad_) {
  __shared__ float Ws[128 * 128];  // [k][col], 64 KB
  __shared__ float Xs[32 * 128];   // [row][k], 16 KB
  const int tid = threadIdx.x;
  for (int i = tid; i < 4096; i += 256)
    ((float4*)Ws)[i] = ((const float4*)W)[i];
  const long row0 = (long)blockIdx.x * 32;
  for (int i = tid; i < 1024; i += 256) {
    long r = row0 + (i >> 5);
    if (r >= n) r = n - 1;
    float4 v = ((const float4*)X)[r * 32 + (i & 31)];
    if (bnss) {
      const int cg = i & 31;
      float4 sc = ((const float4*)bnss)[cg];
      float4 sh = ((const float4*)bnss)[32 + cg];
      v.x = fmaxf(fmaf(v.x, sc.x, sh.x), 0.f);
      v.y = fmaxf(fmaf(v.y, sc.y, sh.y), 0.f);
      v.z = fmaxf(fmaf(v.z, sc.z, sh.z), 0.f);
      v.w = fmaxf(fmaf(v.w, sc.w, sh.w), 0.f);
    }
    ((float4*)Xs)[i] = v;
  }
  __syncthreads();
  const int colg = tid & 31;
  const int rowg = tid >> 5;
  float acc[4][4];
#pragma unroll
  for (int r = 0; r < 4; ++r)
#pragma unroll
    for (int c = 0; c < 4; ++c) acc[r][c] = 0.f;

  for (int k = 0; k < 128; k += 4) {
    float4 w[4];
#pragma unroll
    for (int kk = 0; kk < 4; ++kk)
      w[kk] = *(const float4*)&Ws[(k + kk) * 128 + colg * 4];
#pragma unroll
    for (int r = 0; r < 4; ++r) {
      float4 x4 = *(const float4*)&Xs[(rowg * 4 + r) * 128 + k];
      acc[r][0] = fmaf(x4.x, w[0].x, acc[r][0]);
      acc[r][1] = fmaf(x4.x, w[0].y, acc[r][1]);
      acc[r][2] = fmaf(x4.x, w[0].z, acc[r][2]);
      acc[r][3] = fmaf(x4.x, w[0].w, acc[r][3]);
      acc[r][0] = fmaf(x4.y, w[1].x, acc[r][0]);
      acc[r][1] = fmaf(x4.y, w[1].y, acc[r][1]);
      acc[r][2] = fmaf(x4.y, w[1].z, acc[r][2]);
      acc[r][3] = fmaf(x4.y, w[1].w, acc[r][3]);
      acc[r][0] = fmaf(x4.z, w[2].x, acc[r][0]);
      acc[r][1] = fmaf(x4.z, w[2].y, acc[r][1]);
      acc[r][2] = fmaf(x4.z, w[2].z, acc[r][2]);
      acc[r][3] = fmaf(x4.z, w[2].w, acc[r][3]);
      acc[r][0] = fmaf(x4.w, w[3].x, acc[r][0]);
      acc[r][1] = fmaf(x4.w, w[3].y, acc[r][1]);
      acc[r][2] = fmaf(x4.w, w[3].z, acc[r][2]);
      acc[r][3] = fmaf(x4.w, w[3].w, acc[r][3]);
    }
  }

  const float4 asv = ((const float4*)a_src)[colg];
  const float4 adv = ((const float4*)a_dst)[colg];
  const int hd = colg >> 3;
#pragma unroll
  for (int r = 0; r < 4; ++r) {
    const long row = row0 + rowg * 4 + r;
    if (row < n) {
      uint2 p;
      p.x = pack_bf16x2(acc[r][0], acc[r][1]);
      p.y = pack_bf16x2(acc[r][2], acc[r][3]);
      ((uint2*)Hb)[row * 32 + colg] = p;
    }
    float sp = acc[r][0] * asv.x + acc[r][1] * asv.y + acc[r][2] * asv.z +
               acc[r][3] * asv.w;
    float dp = acc[r][0] * adv.x + acc[r][1] * adv.y + acc[r][2] * adv.z +
               acc[r][3] * adv.w;
#pragma unroll
    for (int off = 4; off > 0; off >>= 1) {
      sp += __shfl_down(sp, off, 8);
      dp += __shfl_down(dp, off, 8);
    }
    if ((colg & 7) == 0 && row < n) {
      as_[row * 4 + hd] = sp;
      ad_[row * 4 + hd] = dp;
    }
  }
}

// ---------------- CSR build via dst-bucket binning --------------------------
// bucket b = dst >> 7 (128 nodes/bucket).

// 1) per-bucket edge histogram (LDS-aggregated)
__global__ __launch_bounds__(256) void k_hist(const int* __restrict__ ei,
                                              int E, int NB,
                                              int* __restrict__ bcnt) {
  __shared__ int hist[MAXNB];
  for (int i = threadIdx.x; i < NB; i += 256) hist[i] = 0;
  __syncthreads();
  const int e0 = blockIdx.x * 4096;
#pragma unroll
  for (int k = 0; k < 16; ++k) {
    int e = e0 + k * 256 + threadIdx.x;
    if (e < E) atomicAdd(&hist[ei[E + e] >> 7], 1);
  }
  __syncthreads();
  for (int i = threadIdx.x; i < NB; i += 256) {
    int c = hist[i];
    if (c) atomicAdd(&bcnt[i], c);
  }
}

// 2) exclusive prefix over bucket counts (single block)
__global__ __launch_bounds__(1024) void k_bprefix(const int* __restrict__ bcnt,
                                                  int NB,
                                                  int* __restrict__ bstart,
                                                  int* __restrict__ bcur) {
  __shared__ int sh[1024];
  const int t = threadIdx.x;
  int v = (t < NB) ? bcnt[t] : 0;
  sh[t] = v;
  __syncthreads();
  for (int off = 1; off < 1024; off <<= 1) {
    int u = (t >= off) ? sh[t - off] : 0;
    __syncthreads();
    sh[t] += u;
    __syncthreads();
  }
  if (t < NB) {
    int ex = sh[t] - v;
    bstart[t] = ex;
    bcur[t] = ex;
    if (t == NB - 1) bstart[NB] = sh[t];
  }
}

// 3) scatter edges into bucket regions, packed (src<<7)|(dst&127)
__global__ __launch_bounds__(256) void k_scatter(const int* __restrict__ ei,
                                                 int E, int NB,
                                                 int* __restrict__ bcur,
                                                 int* __restrict__ packed) {
  __shared__ int hist[MAXNB];
  __shared__ int hbase[MAXNB];
  for (int i = threadIdx.x; i < NB; i += 256) hist[i] = 0;
  __syncthreads();
  const int e0 = blockIdx.x * 4096;
  int myb[16], myv[16];
#pragma unroll
  for (int k = 0; k < 16; ++k) {
    int e = e0 + k * 256 + threadIdx.x;
    myb[k] = -1;
    myv[k] = 0;
    if (e < E) {
      int s = ei[e], d = ei[E + e];
      myb[k] = d >> 7;
      myv[k] = (s << 7) | (d & 127);
      atomicAdd(&hist[myb[k]], 1);
    }
  }
  __syncthreads();
  for (int i = threadIdx.x; i < NB; i += 256) {
    int c = hist[i];
    hbase[i] = c ? atomicAdd(&bcur[i], c) : 0;
    hist[i] = 0;
  }
  __syncthreads();
#pragma unroll
  for (int k = 0; k < 16; ++k) {
    if (myb[k] >= 0) {
      int p = hbase[myb[k]] + atomicAdd(&hist[myb[k]], 1);
      packed[p] = myv[k];
    }
  }
}

// 4) per-bucket local CSR: degrees, offsets, self-loop slot, src scatter
__global__ __launch_bounds__(256) void k_local(const int* __restrict__ packed,
                                               const int* __restrict__ bstart,
                                               int n, int* __restrict__ srcs,
                                               int* __restrict__ offs,
                                               int* __restrict__ deg) {
  const int b = blockIdx.x;
  const int node0 = b << 7;
  const int nn = min(128, n - node0);
  const int e0 = bstart[b], e1 = bstart[b + 1];
  __shared__ int dcnt[128], cur[128], scan[128];
  const int tid = threadIdx.x;
  if (tid < 128) dcnt[tid] = 0;
  __syncthreads();
  for (int i = e0 + tid; i < e1; i += 256)
    atomicAdd(&dcnt[packed[i] & 127], 1);
  __syncthreads();
  int v = 0;
  if (tid < 128) {
    v = (tid < nn) ? dcnt[tid] + 1 : 0;  // +1 = self-loop slot
    scan[tid] = v;
  }
  __syncthreads();
  for (int off = 1; off < 128; off <<= 1) {
    int u = 0;
    if (tid < 128 && tid >= off) u = scan[tid - off];
    __syncthreads();
    if (tid < 128) scan[tid] += u;
    __syncthreads();
  }
  if (tid < nn) {
    const int o = e0 + node0 + (scan[tid] - v);  // global CSR offset
    offs[node0 + tid] = o;
    deg[node0 + tid] = dcnt[tid];
    srcs[o] = node0 + tid;  // self-loop first
    cur[tid] = o + 1;
  }
  __syncthreads();
  for (int i = e0 + tid; i < e1; i += 256) {
    const int pv = packed[i];
    const int p = atomicAdd(&cur[pv & 127], 1);
    srcs[p] = pv >> 7;
  }
}

// ---------------- fused GAT aggregation: single pass, no atomics ------------
__global__ __launch_bounds__(256) void k_agg(
    const int* __restrict__ offs, const int* __restrict__ deg,
    const int* __restrict__ srcs, const unsigned* __restrict__ Hb,
    const float* __restrict__ as_, const float* __restrict__ ad_,
    float* __restrict__ out, int n) {
  const int node = blockIdx.x * 4 + (threadIdx.x >> 6);
  if (node >= n) return;
  const int t = threadIdx.x & 63;
  const int th = t >> 4;
  const int j16 = t & 15;
  const int o0 = offs[node];
  const int dg = deg[node] + 1;  // + self-loop
  const float adv = ad_[node * 4 + th];

  float den = 0.f;
  float2 acc = make_float2(0.f, 0.f);

  for (int base = 0; base < dg; base += 16) {
    const int j = base + j16;
    int s = 0;
    float e = 0.f;
    if (j < dg) {
      s = srcs[o0 + j];
      float l = as_[s * 4 + th] + adv;
      l = l >= 0.f ? l : 0.2f * l;
      e = __expf(fminf(l, 80.f));
    }
    den += e;
#pragma unroll
    for (int jj = 0; jj < 16; ++jj) {
      const int ss = __shfl(s, jj, 64);
      const float w = __shfl(e, (t & 48) | jj, 64);
      const unsigned hv = Hb[(long)ss * 64 + t];
      acc.x = fmaf(w, __uint_as_float(hv << 16), acc.x);
      acc.y = fmaf(w, __uint_as_float(hv & 0xffff0000u), acc.y);
    }
  }
#pragma unroll
  for (int off = 8; off > 0; off >>= 1) den += __shfl_xor(den, off, 64);
  const float invden = 1.f / (den + 1e-16f);
  acc.x *= invden;
  acc.y *= invden;
  ((float2*)out)[(long)node * 64 + t] = acc;
}

// ---------------- BN stats / fold / apply -----------------------------------
__global__ __launch_bounds__(256) void k_stats(const float* __restrict__ V,
                                               float* __restrict__ stats,
                                               int n) {
  const int tid = threadIdx.x;
  const int c = tid & 127, half = tid >> 7;
  float s = 0.f, s2 = 0.f;
  for (int r = blockIdx.x * 2 + half; r < n; r += gridDim.x * 2) {
    float v = V[(long)r * 128 + c];
    s += v;
    s2 = fmaf(v, v, s2);
  }
  __shared__ float sh[256];
  sh[tid] = s;
  __syncthreads();
  if (half == 0) s += sh[tid + 128];
  __syncthreads();
  sh[tid] = s2;
  __syncthreads();
  if (half == 0) {
    s2 += sh[tid + 128];
    atomicAdd(&stats[c], s);
    atomicAdd(&stats[128 + c], s2);
  }
}

__global__ void k_finalize(const float* __restrict__ stats,
                           const float* __restrict__ gamma,
                           const float* __restrict__ beta,
                           float* __restrict__ ss, float invN) {
  int c = threadIdx.x;  // 128 threads
  float mean = stats[c] * invN;
  float var = stats[128 + c] * invN - mean * mean;
  float sc = gamma[c] * rsqrtf(var + 1e-5f);
  ss[c] = sc;
  ss[128 + c] = beta[c] - mean * sc;
}

__global__ __launch_bounds__(256) void k_bn_apply(
    const float* __restrict__ V, const float* __restrict__ ss,
    const float* __restrict__ skip, float* __restrict__ Y, int total4) {
  const int i = blockIdx.x * 256 + threadIdx.x;
  if (i >= total4) return;
  const int c4 = i & 31;
  float4 v = ((const float4*)V)[i];
  float4 sc = ((const float4*)ss)[c4];
  float4 sh = ((const float4*)ss)[32 + c4];
  float4 s = ((const float4*)skip)[i];
  float4 y;
  y.x = fmaxf(fmaf(v.x, sc.x, sh.x) + s.x, 0.f);
  y.y = fmaxf(fmaf(v.y, sc.y, sh.y) + s.y, 0.f);
  y.z = fmaxf(fmaf(v.z, sc.z, sh.z) + s.z, 0.f);
  y.w = fmaxf(fmaf(v.w, sc.w, sh.w) + s.w, 0.f);
  ((float4*)Y)[i] = y;
}

extern "C" void kernel_launch(void* const* d_in, const int* in_sizes, int n_in,
                              void* d_out, int out_size, void* d_ws,
                              size_t ws_size, hipStream_t stream) {
  const float* x = (const float*)d_in[0];
  const int* ei = (const int*)d_in[1];
  const float* W1 = (const float*)d_in[2];
  const float* a_src1 = (const float*)d_in[3];
  const float* a_dst1 = (const float*)d_in[4];
  // b1 cancels in BN
  const float* gamma1 = (const float*)d_in[6];
  const float* beta1 = (const float*)d_in[7];
  const float* W2 = (const float*)d_in[8];
  const float* a_src2 = (const float*)d_in[9];
  const float* a_dst2 = (const float*)d_in[10];
  // b2 cancels in BN
  const float* gamma2 = (const float*)d_in[12];
  const float* beta2 = (const float*)d_in[13];

  const int n = in_sizes[0] / 128;
  const int E = in_sizes[1] / 2;
  const int EP = E + n;
  const int NB = (n + 127) >> 7;   // dst buckets (<= MAXNB)
  const int EB = (E + 4095) / 4096;

  char* w = (char*)d_ws;
  const size_t szNC = (size_t)n * 128 * sizeof(float);
  unsigned* Hb = (unsigned*)w;  w += (size_t)n * 64 * sizeof(unsigned);
  float* Bagg = (float*)w;      w += szNC;
  float* as_ = (float*)w;       w += (size_t)n * 4 * sizeof(float);
  float* ad_ = (float*)w;       w += (size_t)n * 4 * sizeof(float);
  int* srcs = (int*)w;          w += (size_t)EP * sizeof(int);
  int* packed = (int*)w;        w += (size_t)E * sizeof(int);
  int* deg = (int*)w;           w += (size_t)n * sizeof(int);
  int* offs = (int*)w;          w += (size_t)n * sizeof(int);
  int* bcnt = (int*)w;          w += (size_t)NB * sizeof(int);
  int* bstart = (int*)w;        w += (size_t)(NB + 1) * sizeof(int);
  int* bcur = (int*)w;          w += (size_t)NB * sizeof(int);
  float* stats = (float*)w;     w += 256 * sizeof(float);
  float* ss1 = (float*)w;       w += 256 * sizeof(float);
  float* ss2 = (float*)w;       w += 256 * sizeof(float);

  // ---- CSR build (bucket binning; shared by both layers) ----
  hipMemsetAsync(bcnt, 0, (size_t)NB * sizeof(int), stream);
  k_hist<<<EB, 256, 0, stream>>>(ei, E, NB, bcnt);
  k_bprefix<<<1, 1024, 0, stream>>>(bcnt, NB, bstart, bcur);
  k_scatter<<<EB, 256, 0, stream>>>(ei, E, NB, bcur, packed);
  k_local<<<NB, 256, 0, stream>>>(packed, bstart, n, srcs, offs, deg);

  // ---- layer 1 ----
  k_gemm<<<(n + 31) / 32, 256, 0, stream>>>(x, W1, Hb, n, nullptr, a_src1,
                                            a_dst1, as_, ad_);
  k_agg<<<(n + 3) / 4, 256, 0, stream>>>(offs, deg, srcs, Hb, as_, ad_, Bagg,
                                         n);
  hipMemsetAsync(stats, 0, 256 * sizeof(float), stream);
  k_stats<<<256, 256, 0, stream>>>(Bagg, stats, n);
  k_finalize<<<1, 128, 0, stream>>>(stats, gamma1, beta1, ss1,
                                    1.0f / (float)n);

  // ---- layer 2 (BN1+ReLU folded into GEMM2's X load; y1 never stored) ----
  k_gemm<<<(n + 31) / 32, 256, 0, stream>>>(Bagg, W2, Hb, n, ss1, a_src2,
                                            a_dst2, as_, ad_);
  k_agg<<<(n + 3) / 4, 256, 0, stream>>>(offs, deg, srcs, Hb, as_, ad_, Bagg,
                                         n);
  hipMemsetAsync(stats, 0, 256 * sizeof(float), stream);
  k_stats<<<256, 256, 0, stream>>>(Bagg, stats, n);
  k_finalize<<<1, 128, 0, stream>>>(stats, gamma2, beta2, ss2,
                                    1.0f / (float)n);
  k_bn_apply<<<(n * 32 + 255) / 256, 256, 0, stream>>>(Bagg, ss2, x,
                                                       (float*)d_out, n * 32);
}

// Round 5
// 553.660 us; speedup vs baseline: 5.7581x; 1.1428x over previous
//
#include <hip/hip_runtime.h>

#define MAXNB 1024  // max dst-buckets (128 nodes each) -> supports n <= 131072

typedef __attribute__((ext_vector_type(8))) short bf8;    // 8 bf16 (4 VGPRs)
typedef __attribute__((ext_vector_type(4))) float f32x4;  // MFMA C/D

// pack two fp32 -> two bf16 (RNE) in one uint (a = low = even channel)
__device__ __forceinline__ unsigned pack_bf16x2(float a, float b) {
  unsigned ua = __float_as_uint(a);
  ua = (ua + 0x7fffu + ((ua >> 16) & 1u)) >> 16;
  unsigned ub = __float_as_uint(b);
  ub = (ub + 0x7fffu + ((ub >> 16) & 1u)) >> 16;
  return ua | (ub << 16);
}

// ---- W prep: fp32 [128k][128c] -> bf16 B-fragments for 16x16x32 MFMA ------
// frag = ct*4+kc; lane: col = ct*16+(lane&15), k = kc*32+(lane>>4)*8+j.
// Wf[frag*64 + lane] = uint4 of 8 bf16 (k ascending).
__global__ __launch_bounds__(256) void k_wprep(const float* __restrict__ W,
                                               uint4* __restrict__ Wf) {
  const int t = blockIdx.x * 256 + threadIdx.x;  // 0..2047
  const int frag = t >> 6, lane = t & 63;
  const int ct = frag >> 2, kc = frag & 3;
  const int col = ct * 16 + (lane & 15);
  const int k0 = kc * 32 + (lane >> 4) * 8;
  unsigned p[4];
#pragma unroll
  for (int j = 0; j < 4; ++j)
    p[j] = pack_bf16x2(W[(k0 + 2 * j) * 128 + col],
                       W[(k0 + 2 * j + 1) * 128 + col]);
  Wf[t] = make_uint4(p[0], p[1], p[2], p[3]);
}

// ---- MFMA GEMM: H(bf16) = X[n,128] @ W[128,128], fused alpha dots ---------
// 256 thr = 4 waves; wave w -> rows row0+w*16..+15. 32 MFMAs per wave.
// Epilogue: C -> LDS staging (fp32) -> coalesced bf16 pack + per-(row,head)
// alpha dot products (no cross-lane reduce needed).
__global__ __launch_bounds__(256) void k_gemm(
    const float* __restrict__ X, const uint4* __restrict__ Wf,
    unsigned* __restrict__ Hb, int n, const float* __restrict__ bnss,
    const float* __restrict__ a_src, const float* __restrict__ a_dst,
    float* __restrict__ as_, float* __restrict__ ad_) {
  __shared__ float stag[64 * 132];  // 33792 B
  const int tid = threadIdx.x;
  const int w = tid >> 6, lane = tid & 63;
  const int q = lane >> 4, nl = lane & 15;
  const long row0 = (long)blockIdx.x * 64;
  long rowA = row0 + w * 16 + nl;
  if (rowA >= n) rowA = n - 1;  // clamp; stores are guarded

  // A fragments: 4 K-chunks, 8 consecutive k each (fp32 -> bf16 in-register)
  bf8 a[4];
#pragma unroll
  for (int kc = 0; kc < 4; ++kc) {
    const float* p = X + rowA * 128 + kc * 32 + q * 8;
    float4 v0 = *(const float4*)p;
    float4 v1 = *(const float4*)(p + 4);
    if (bnss) {  // fold previous layer's BN+ReLU: x = relu(x*sc+sh)
      const int kb = kc * 32 + q * 8;
      float4 s0 = *(const float4*)(bnss + kb);
      float4 s1 = *(const float4*)(bnss + kb + 4);
      float4 h0 = *(const float4*)(bnss + 128 + kb);
      float4 h1 = *(const float4*)(bnss + 128 + kb + 4);
      v0.x = fmaxf(fmaf(v0.x, s0.x, h0.x), 0.f);
      v0.y = fmaxf(fmaf(v0.y, s0.y, h0.y), 0.f);
      v0.z = fmaxf(fmaf(v0.z, s0.z, h0.z), 0.f);
      v0.w = fmaxf(fmaf(v0.w, s0.w, h0.w), 0.f);
      v1.x = fmaxf(fmaf(v1.x, s1.x, h1.x), 0.f);
      v1.y = fmaxf(fmaf(v1.y, s1.y, h1.y), 0.f);
      v1.z = fmaxf(fmaf(v1.z, s1.z, h1.z), 0.f);
      v1.w = fmaxf(fmaf(v1.w, s1.w, h1.w), 0.f);
    }
    union { uint4 u; bf8 v; } cv;
    cv.u = make_uint4(pack_bf16x2(v0.x, v0.y), pack_bf16x2(v0.z, v0.w),
                      pack_bf16x2(v1.x, v1.y), pack_bf16x2(v1.z, v1.w));
    a[kc] = cv.v;
  }

  // main: 8 col-tiles x 4 K-chunks; B frags from L2-resident Wf table
  f32x4 acc[8];
#pragma unroll
  for (int ct = 0; ct < 8; ++ct) {
    f32x4 c = {0.f, 0.f, 0.f, 0.f};
#pragma unroll
    for (int kc = 0; kc < 4; ++kc) {
      union { uint4 u; bf8 v; } b;
      b.u = Wf[(ct * 4 + kc) * 64 + lane];
      c = __builtin_amdgcn_mfma_f32_16x16x32_bf16(a[kc], b.v, c, 0, 0, 0);
    }
    acc[ct] = c;
  }

  // C/D layout: col = ct*16 + nl, local row = w*16 + q*4 + r
  const int lr = w * 16 + q * 4;
#pragma unroll
  for (int ct = 0; ct < 8; ++ct)
#pragma unroll
    for (int r = 0; r < 4; ++r)
      stag[(lr + r) * 132 + ct * 16 + nl] = acc[ct][r];
  __syncthreads();

  // pack + alpha: thread -> row = tid>>2 (64 rows), head seg = tid&3
  {
    const int row = tid >> 2, seg = tid & 3;
    const long grow = row0 + row;
    if (grow < n) {
      float sp = 0.f, dp = 0.f;
      const float* p = &stag[row * 132 + seg * 32];
#pragma unroll
      for (int i = 0; i < 8; ++i) {
        float4 h4 = *(const float4*)(p + i * 4);
        float4 s4 = ((const float4*)a_src)[seg * 8 + i];
        float4 d4 = ((const float4*)a_dst)[seg * 8 + i];
        sp += h4.x * s4.x + h4.y * s4.y + h4.z * s4.z + h4.w * s4.w;
        dp += h4.x * d4.x + h4.y * d4.y + h4.z * d4.z + h4.w * d4.w;
        uint2 o;
        o.x = pack_bf16x2(h4.x, h4.y);
        o.y = pack_bf16x2(h4.z, h4.w);
        ((uint2*)Hb)[grow * 32 + seg * 8 + i] = o;
      }
      as_[grow * 4 + seg] = sp;
      ad_[grow * 4 + seg] = dp;
    }
  }
}

// ---------------- CSR build via dst-bucket binning --------------------------
__global__ __launch_bounds__(256) void k_hist(const int* __restrict__ ei,
                                              int E, int NB,
                                              int* __restrict__ bcnt) {
  __shared__ int hist[MAXNB];
  for (int i = threadIdx.x; i < NB; i += 256) hist[i] = 0;
  __syncthreads();
  const int e0 = blockIdx.x * 4096;
#pragma unroll
  for (int k = 0; k < 16; ++k) {
    int e = e0 + k * 256 + threadIdx.x;
    if (e < E) atomicAdd(&hist[ei[E + e] >> 7], 1);
  }
  __syncthreads();
  for (int i = threadIdx.x; i < NB; i += 256) {
    int c = hist[i];
    if (c) atomicAdd(&bcnt[i], c);
  }
}

__global__ __launch_bounds__(1024) void k_bprefix(const int* __restrict__ bcnt,
                                                  int NB,
                                                  int* __restrict__ bstart,
                                                  int* __restrict__ bcur) {
  __shared__ int sh[1024];
  const int t = threadIdx.x;
  int v = (t < NB) ? bcnt[t] : 0;
  sh[t] = v;
  __syncthreads();
  for (int off = 1; off < 1024; off <<= 1) {
    int u = (t >= off) ? sh[t - off] : 0;
    __syncthreads();
    sh[t] += u;
    __syncthreads();
  }
  if (t < NB) {
    int ex = sh[t] - v;
    bstart[t] = ex;
    bcur[t] = ex;
    if (t == NB - 1) bstart[NB] = sh[t];
  }
}

__global__ __launch_bounds__(256) void k_scatter(const int* __restrict__ ei,
                                                 int E, int NB,
                                                 int* __restrict__ bcur,
                                                 int* __restrict__ packed) {
  __shared__ int hist[MAXNB];
  __shared__ int hbase[MAXNB];
  for (int i = threadIdx.x; i < NB; i += 256) hist[i] = 0;
  __syncthreads();
  const int e0 = blockIdx.x * 4096;
  int myb[16], myv[16];
#pragma unroll
  for (int k = 0; k < 16; ++k) {
    int e = e0 + k * 256 + threadIdx.x;
    myb[k] = -1;
    myv[k] = 0;
    if (e < E) {
      int s = ei[e], d = ei[E + e];
      myb[k] = d >> 7;
      myv[k] = (s << 7) | (d & 127);
      atomicAdd(&hist[myb[k]], 1);
    }
  }
  __syncthreads();
  for (int i = threadIdx.x; i < NB; i += 256) {
    int c = hist[i];
    hbase[i] = c ? atomicAdd(&bcur[i], c) : 0;
    hist[i] = 0;
  }
  __syncthreads();
#pragma unroll
  for (int k = 0; k < 16; ++k) {
    if (myb[k] >= 0) {
      int p = hbase[myb[k]] + atomicAdd(&hist[myb[k]], 1);
      packed[p] = myv[k];
    }
  }
}

__global__ __launch_bounds__(256) void k_local(const int* __restrict__ packed,
                                               const int* __restrict__ bstart,
                                               int n, int* __restrict__ srcs,
                                               int* __restrict__ offs,
                                               int* __restrict__ deg) {
  const int b = blockIdx.x;
  const int node0 = b << 7;
  const int nn = min(128, n - node0);
  const int e0 = bstart[b], e1 = bstart[b + 1];
  __shared__ int dcnt[128], cur[128], scan[128];
  const int tid = threadIdx.x;
  if (tid < 128) dcnt[tid] = 0;
  __syncthreads();
  for (int i = e0 + tid; i < e1; i += 256)
    atomicAdd(&dcnt[packed[i] & 127], 1);
  __syncthreads();
  int v = 0;
  if (tid < 128) {
    v = (tid < nn) ? dcnt[tid] + 1 : 0;  // +1 = self-loop slot
    scan[tid] = v;
  }
  __syncthreads();
  for (int off = 1; off < 128; off <<= 1) {
    int u = 0;
    if (tid < 128 && tid >= off) u = scan[tid - off];
    __syncthreads();
    if (tid < 128) scan[tid] += u;
    __syncthreads();
  }
  if (tid < nn) {
    const int o = e0 + node0 + (scan[tid] - v);  // global CSR offset
    offs[node0 + tid] = o;
    deg[node0 + tid] = dcnt[tid];
    srcs[o] = node0 + tid;  // self-loop first
    cur[tid] = o + 1;
  }
  __syncthreads();
  for (int i = e0 + tid; i < e1; i += 256) {
    const int pv = packed[i];
    const int p = atomicAdd(&cur[pv & 127], 1);
    srcs[p] = pv >> 7;
  }
}

// ---------------- fused GAT aggregation: single pass, no atomics ------------
__global__ __launch_bounds__(256) void k_agg(
    const int* __restrict__ offs, const int* __restrict__ deg,
    const int* __restrict__ srcs, const unsigned* __restrict__ Hb,
    const float* __restrict__ as_, const float* __restrict__ ad_,
    float* __restrict__ out, int n) {
  const int node = blockIdx.x * 4 + (threadIdx.x >> 6);
  if (node >= n) return;
  const int t = threadIdx.x & 63;
  const int th = t >> 4;
  const int j16 = t & 15;
  const int o0 = offs[node];
  const int dg = deg[node] + 1;  // + self-loop
  const float adv = ad_[node * 4 + th];

  float den = 0.f;
  float2 acc = make_float2(0.f, 0.f);

  for (int base = 0; base < dg; base += 16) {
    const int j = base + j16;
    int s = 0;
    float e = 0.f;
    if (j < dg) {
      s = srcs[o0 + j];
      float l = as_[s * 4 + th] + adv;
      l = l >= 0.f ? l : 0.2f * l;
      e = __expf(fminf(l, 80.f));
    }
    den += e;
#pragma unroll
    for (int jj = 0; jj < 16; ++jj) {
      const int ss = __shfl(s, jj, 64);
      const float w = __shfl(e, (t & 48) | jj, 64);
      const unsigned hv = Hb[(long)ss * 64 + t];
      acc.x = fmaf(w, __uint_as_float(hv << 16), acc.x);
      acc.y = fmaf(w, __uint_as_float(hv & 0xffff0000u), acc.y);
    }
  }
#pragma unroll
  for (int off = 8; off > 0; off >>= 1) den += __shfl_xor(den, off, 64);
  const float invden = 1.f / (den + 1e-16f);
  acc.x *= invden;
  acc.y *= invden;
  ((float2*)out)[(long)node * 64 + t] = acc;
}

// ---------------- BN stats / fold / apply -----------------------------------
__global__ __launch_bounds__(256) void k_stats(const float* __restrict__ V,
                                               float* __restrict__ stats,
                                               int n) {
  const int tid = threadIdx.x;
  const int c = tid & 127, half = tid >> 7;
  float s = 0.f, s2 = 0.f;
  for (int r = blockIdx.x * 2 + half; r < n; r += gridDim.x * 2) {
    float v = V[(long)r * 128 + c];
    s += v;
    s2 = fmaf(v, v, s2);
  }
  __shared__ float sh[256];
  sh[tid] = s;
  __syncthreads();
  if (half == 0) s += sh[tid + 128];
  __syncthreads();
  sh[tid] = s2;
  __syncthreads();
  if (half == 0) {
    s2 += sh[tid + 128];
    atomicAdd(&stats[c], s);
    atomicAdd(&stats[128 + c], s2);
  }
}

__global__ void k_finalize(const float* __restrict__ stats,
                           const float* __restrict__ gamma,
                           const float* __restrict__ beta,
                           float* __restrict__ ss, float invN) {
  int c = threadIdx.x;  // 128 threads
  float mean = stats[c] * invN;
  float var = stats[128 + c] * invN - mean * mean;
  float sc = gamma[c] * rsqrtf(var + 1e-5f);
  ss[c] = sc;
  ss[128 + c] = beta[c] - mean * sc;
}

__global__ __launch_bounds__(256) void k_bn_apply(
    const float* __restrict__ V, const float* __restrict__ ss,
    const float* __restrict__ skip, float* __restrict__ Y, int total4) {
  const int i = blockIdx.x * 256 + threadIdx.x;
  if (i >= total4) return;
  const int c4 = i & 31;
  float4 v = ((const float4*)V)[i];
  float4 sc = ((const float4*)ss)[c4];
  float4 sh = ((const float4*)ss)[32 + c4];
  float4 s = ((const float4*)skip)[i];
  float4 y;
  y.x = fmaxf(fmaf(v.x, sc.x, sh.x) + s.x, 0.f);
  y.y = fmaxf(fmaf(v.y, sc.y, sh.y) + s.y, 0.f);
  y.z = fmaxf(fmaf(v.z, sc.z, sh.z) + s.z, 0.f);
  y.w = fmaxf(fmaf(v.w, sc.w, sh.w) + s.w, 0.f);
  ((float4*)Y)[i] = y;
}

extern "C" void kernel_launch(void* const* d_in, const int* in_sizes, int n_in,
                              void* d_out, int out_size, void* d_ws,
                              size_t ws_size, hipStream_t stream) {
  const float* x = (const float*)d_in[0];
  const int* ei = (const int*)d_in[1];
  const float* W1 = (const float*)d_in[2];
  const float* a_src1 = (const float*)d_in[3];
  const float* a_dst1 = (const float*)d_in[4];
  // b1 cancels in BN
  const float* gamma1 = (const float*)d_in[6];
  const float* beta1 = (const float*)d_in[7];
  const float* W2 = (const float*)d_in[8];
  const float* a_src2 = (const float*)d_in[9];
  const float* a_dst2 = (const float*)d_in[10];
  // b2 cancels in BN
  const float* gamma2 = (const float*)d_in[12];
  const float* beta2 = (const float*)d_in[13];

  const int n = in_sizes[0] / 128;
  const int E = in_sizes[1] / 2;
  const int EP = E + n;
  const int NB = (n + 127) >> 7;  // dst buckets (<= MAXNB)
  const int EB = (E + 4095) / 4096;

  char* w = (char*)d_ws;
  const size_t szNC = (size_t)n * 128 * sizeof(float);
  unsigned* Hb = (unsigned*)w;  w += (size_t)n * 64 * sizeof(unsigned);
  float* Bagg = (float*)w;      w += szNC;
  float* as_ = (float*)w;       w += (size_t)n * 4 * sizeof(float);
  float* ad_ = (float*)w;       w += (size_t)n * 4 * sizeof(float);
  int* srcs = (int*)w;          w += (size_t)EP * sizeof(int);
  int* packed = (int*)w;        w += (size_t)E * sizeof(int);
  int* deg = (int*)w;           w += (size_t)n * sizeof(int);
  int* offs = (int*)w;          w += (size_t)n * sizeof(int);
  int* bcnt = (int*)w;          w += (size_t)NB * sizeof(int);
  int* bstart = (int*)w;        w += (size_t)(NB + 1) * sizeof(int);
  int* bcur = (int*)w;          w += (size_t)NB * sizeof(int);
  uint4* Wf1 = (uint4*)w;       w += 2048 * sizeof(uint4);
  uint4* Wf2 = (uint4*)w;       w += 2048 * sizeof(uint4);
  float* stats = (float*)w;     w += 256 * sizeof(float);
  float* ss1 = (float*)w;       w += 256 * sizeof(float);
  float* ss2 = (float*)w;       w += 256 * sizeof(float);

  // ---- W fragment prep (once per launch) ----
  k_wprep<<<8, 256, 0, stream>>>(W1, Wf1);
  k_wprep<<<8, 256, 0, stream>>>(W2, Wf2);

  // ---- CSR build (bucket binning; shared by both layers) ----
  hipMemsetAsync(bcnt, 0, (size_t)NB * sizeof(int), stream);
  k_hist<<<EB, 256, 0, stream>>>(ei, E, NB, bcnt);
  k_bprefix<<<1, 1024, 0, stream>>>(bcnt, NB, bstart, bcur);
  k_scatter<<<EB, 256, 0, stream>>>(ei, E, NB, bcur, packed);
  k_local<<<NB, 256, 0, stream>>>(packed, bstart, n, srcs, offs, deg);

  // ---- layer 1 ----
  k_gemm<<<(n + 63) / 64, 256, 0, stream>>>(x, Wf1, Hb, n, nullptr, a_src1,
                                            a_dst1, as_, ad_);
  k_agg<<<(n + 3) / 4, 256, 0, stream>>>(offs, deg, srcs, Hb, as_, ad_, Bagg,
                                         n);
  hipMemsetAsync(stats, 0, 256 * sizeof(float), stream);
  k_stats<<<256, 256, 0, stream>>>(Bagg, stats, n);
  k_finalize<<<1, 128, 0, stream>>>(stats, gamma1, beta1, ss1,
                                    1.0f / (float)n);

  // ---- layer 2 (BN1+ReLU folded into GEMM2's X load; y1 never stored) ----
  k_gemm<<<(n + 63) / 64, 256, 0, stream>>>(Bagg, Wf2, Hb, n, ss1, a_src2,
                                            a_dst2, as_, ad_);
  k_agg<<<(n + 3) / 4, 256, 0, stream>>>(offs, deg, srcs, Hb, as_, ad_, Bagg,
                                         n);
  hipMemsetAsync(stats, 0, 256 * sizeof(float), stream);
  k_stats<<<256, 256, 0, stream>>>(Bagg, stats, n);
  k_finalize<<<1, 128, 0, stream>>>(stats, gamma2, beta2, ss2,
                                    1.0f / (float)n);
  k_bn_apply<<<(n * 32 + 255) / 256, 256, 0, stream>>>(Bagg, ss2, x,
                                                       (float*)d_out, n * 32);
}